// Round 7
// baseline (111.796 us; speedup 1.0000x reference)
//
#include <hip/hip_runtime.h>
#include <hip/hip_bf16.h>
#include <cstdint>

#define N_DIM 4096
#define K_DIM 2048
#define NIT 16   // 32 K-tiles of 64, 2 per iteration

typedef __bf16 bf16x8 __attribute__((ext_vector_type(8)));
typedef float floatx4 __attribute__((ext_vector_type(4)));
typedef unsigned short ushort8 __attribute__((ext_vector_type(8)));
typedef int intx4 __attribute__((ext_vector_type(4)));
typedef unsigned long long ull;

__device__ __forceinline__ unsigned short f2bf(float f) {
    unsigned int u = __builtin_bit_cast(unsigned int, f);
    unsigned int r = (u + 0x7fffu + ((u >> 16) & 1u)) >> 16;  // RNE
    return (unsigned short)r;
}

__device__ __forceinline__ void gld_lds16(const void* g, void* l) {
    __builtin_amdgcn_global_load_lds(
        (const __attribute__((address_space(1))) unsigned int*)g,
        (__attribute__((address_space(3))) unsigned int*)l,
        16, 0, 0);
}

__device__ __forceinline__ void stage_half(const unsigned short* src, unsigned short* ldsWave) {
    gld_lds16(src, ldsWave);                       // rows 0-63 of the half
    gld_lds16(src + 64 * K_DIM, ldsWave + 4096);   // rows 64-127 (+8192 B)
}

// ---------------- Kernel 0: cast fp32 -> bf16, compute row squared norms ----
__global__ __launch_bounds__(256)
void prep_kernel(const float* __restrict__ X, unsigned short* __restrict__ Abf,
                 float* __restrict__ sq) {
    const int row = blockIdx.x;
    const int tid = threadIdx.x;
    const float* xr = X + (size_t)row * K_DIM;
    floatx4 a = *(const floatx4*)(xr + tid * 8);
    floatx4 b = *(const floatx4*)(xr + tid * 8 + 4);
    float s = 0.f;
    ushort8 o;
#pragma unroll
    for (int e = 0; e < 4; ++e) {
        s += a[e] * a[e] + b[e] * b[e];
        o[e] = f2bf(a[e]);
        o[4 + e] = f2bf(b[e]);
    }
    *(ushort8*)(Abf + (size_t)row * K_DIM + tid * 8) = o;
#pragma unroll
    for (int off = 32; off; off >>= 1) s += __shfl_down(s, off);
    __shared__ float wsum[4];
    const int wave = tid >> 6, lane = tid & 63;
    if (lane == 0) wsum[wave] = s;
    __syncthreads();
    if (tid == 0) sq[row] = wsum[0] + wsum[1] + wsum[2] + wsum[3];
}

// ---------------- Kernel 1: 256x256 8-phase bf16 MFMA GEMM + dist epilogue --
// K-loop identical to round-6 (best measured: 67 us, MfmaUtil 42%, 0 bank
// conflicts). NEW: fused rowstats in the epilogue — per-row hardest-pos
// (atomicMax) / hardest-neg (atomicMin) on packed (f32bits(d)<<32 | idx)
// keys; last-index tie-break encoded as idx for max, ~idx for min. LDS
// main buffer reused for the 4-wave combine after the K-loop.
#define RD_A(OFF) { _Pragma("unroll") for (int m_ = 0; m_ < 4; ++m_) { \
    _Pragma("unroll") for (int kk_ = 0; kk_ < 2; ++kk_) { \
        af[m_][kk_] = *(const bf16x8*)(ldsc + (OFF) + rA[m_] + kb[kk_]); } } }
#define RD_B(OFF) { _Pragma("unroll") for (int n_ = 0; n_ < 2; ++n_) { \
    _Pragma("unroll") for (int kk_ = 0; kk_ < 2; ++kk_) { \
        bfv[n_][kk_] = *(const bf16x8*)(ldsc + (OFF) + rB[n_] + kb[kk_]); } } }
#define MMQ(MH, NH) { _Pragma("unroll") for (int m_ = 0; m_ < 4; ++m_) { \
    _Pragma("unroll") for (int n_ = 0; n_ < 2; ++n_) { \
    _Pragma("unroll") for (int kk_ = 0; kk_ < 2; ++kk_) { \
        acc[MH][NH][m_][n_] = __builtin_amdgcn_mfma_f32_16x16x32_bf16( \
            af[m_][kk_], bfv[n_][kk_], acc[MH][NH][m_][n_], 0, 0, 0); } } } }
#define BAR() __builtin_amdgcn_s_barrier()
#define PRIO1() __builtin_amdgcn_s_setprio(1)
#define PRIO0() __builtin_amdgcn_s_setprio(0)
#define VMCNT4() asm volatile("s_waitcnt vmcnt(4)" ::: "memory")
#define VMCNT0() asm volatile("s_waitcnt vmcnt(0)" ::: "memory")

__global__ __launch_bounds__(512, 2)
void gemm_dist(const unsigned short* __restrict__ Abf, const float* __restrict__ sq,
               const int* __restrict__ tgt, float* __restrict__ D,
               ull* __restrict__ gMax, ull* __restrict__ gMin) {
    __shared__ unsigned short lds[65536];   // 128 KB
    __shared__ int sTgtR[256];
    __shared__ int sTgtC[256];
    const char* ldsc = (const char*)lds;
    const int tid = threadIdx.x;
    const int wid = tid >> 6, lane = tid & 63;
    const int wr = wid >> 2, wc = wid & 3;
    const int fr = lane & 15;
    const int key = (fr & 7) << 4;
    const int klin = (lane >> 4) << 4;     // byte offset of 16B k-slot
    int kb[2];
    kb[0] = klin ^ key;
    kb[1] = (64 | klin) ^ key;
    int rA[4], rB[2];
#pragma unroll
    for (int m = 0; m < 4; ++m) rA[m] = (wr * 64 + m * 16 + fr) * 128;
#pragma unroll
    for (int n = 0; n < 2; ++n) rB[n] = (wc * 32 + n * 16 + fr) * 128;

    const int swz = (blockIdx.x & 7) * 32 + (blockIdx.x >> 3);  // XCD-chunked
    const int bi = swz >> 4, bj = swz & 15;
    const int rowC0 = bi * 256, colC0 = bj * 256;

    if (tid < 256) { sTgtR[tid] = tgt[rowC0 + tid]; sTgtC[tid] = tgt[colC0 + tid]; }

    // per-thread staging source (inverse-swizzled k: linear LDS + swz read = identity)
    const int srow = tid >> 3;
    const int ksrc = ((tid & 7) ^ (srow & 7)) << 3;
    const unsigned short* aSt = Abf + (size_t)(rowC0 + srow) * K_DIM + ksrc;
    const unsigned short* bSt = Abf + (size_t)(colC0 + srow) * K_DIM + ksrc;
    // wave-uniform LDS stage bases (ushort offsets)
    unsigned short* Lb0A0 = lds + 0     + wid * 512;
    unsigned short* Lb0A1 = lds + 8192  + wid * 512;
    unsigned short* Lb0B0 = lds + 16384 + wid * 512;
    unsigned short* Lb0B1 = lds + 24576 + wid * 512;
    unsigned short* Lb1A0 = lds + 32768 + wid * 512;
    unsigned short* Lb1A1 = lds + 40960 + wid * 512;
    unsigned short* Lb1B0 = lds + 49152 + wid * 512;
    unsigned short* Lb1B1 = lds + 57344 + wid * 512;

    floatx4 acc[2][2][4][2];
#pragma unroll
    for (int a0 = 0; a0 < 2; ++a0)
#pragma unroll
    for (int a1 = 0; a1 < 2; ++a1)
#pragma unroll
    for (int a2 = 0; a2 < 4; ++a2)
#pragma unroll
    for (int a3 = 0; a3 < 2; ++a3) acc[a0][a1][a2][a3] = (floatx4){0.f, 0.f, 0.f, 0.f};
    bf16x8 af[4][2], bfv[2][2];

    // prologue: t0 {A0,B0,B1,A1} + t1 {A0,B1}; vmcnt(4) = t0 fully landed
    stage_half(aSt,               Lb0A0);
    stage_half(bSt,               Lb0B0);
    stage_half(bSt + 262144,      Lb0B1);
    stage_half(aSt + 262144,      Lb0A1);
    stage_half(aSt + 64,          Lb1A0);
    stage_half(bSt + 262144 + 64, Lb1B1);
    VMCNT4();
    BAR();

    for (int it = 0; it < NIT; ++it) {
        const int t64 = it * 128;           // k-elem base of tile a=2*it
        const bool pf = (it < NIT - 1);
        // ph1: reads A0,B0 | stage (a+1).A1 -> b1A1 | BAR | MMQ(0,0)
        RD_A(0); RD_B(32768);
        stage_half(aSt + 262144 + t64 + 64, Lb1A1);
        BAR(); PRIO1(); MMQ(0, 0); PRIO0();
        // ph2: reads B1 | stage (a+1).B0 -> b1B0 | BAR | MMQ(0,1)
        RD_B(49152);
        stage_half(bSt + t64 + 64, Lb1B0);
        BAR(); PRIO1(); MMQ(0, 1); PRIO0();
        // ph3: reads A1 | stage (a+2).A0 -> b0A0 | BAR | MMQ(1,1)
        RD_A(16384);
        if (pf) stage_half(aSt + t64 + 128, Lb0A0);
        BAR(); PRIO1(); MMQ(1, 1); PRIO0();
        // ph4: reads B0 | stage (a+2).B1 -> b0B1 | vmcnt | BAR | MMQ(1,0)
        RD_B(32768);
        if (pf) stage_half(bSt + 262144 + t64 + 128, Lb0B1);
        if (pf) { VMCNT4(); } else { VMCNT0(); }
        BAR(); PRIO1(); MMQ(1, 0); PRIO0();
        // ph5: reads A0',B0' | stage (a+2).A1 -> b0A1 | BAR | MMQ(0,0)
        RD_A(65536); RD_B(98304);
        if (pf) stage_half(aSt + 262144 + t64 + 128, Lb0A1);
        BAR(); PRIO1(); MMQ(0, 0); PRIO0();
        // ph6: reads B1' | stage (a+2).B0 -> b0B0 | BAR | MMQ(0,1)
        RD_B(114688);
        if (pf) stage_half(bSt + t64 + 128, Lb0B0);
        BAR(); PRIO1(); MMQ(0, 1); PRIO0();
        // ph7: reads A1' | stage (a+3).A0 -> b1A0 | BAR | MMQ(1,1)
        RD_A(81920);
        if (pf) stage_half(aSt + t64 + 192, Lb1A0);
        BAR(); PRIO1(); MMQ(1, 1); PRIO0();
        // ph8: reads B0' | stage (a+3).B1 -> b1B1 | vmcnt | BAR | MMQ(1,0)
        RD_B(98304);
        if (pf) stage_half(bSt + 262144 + t64 + 192, Lb1B1);
        if (pf) { VMCNT4(); } else { VMCNT0(); }
        BAR(); PRIO1(); MMQ(1, 0); PRIO0();
    }

    // ---- epilogue phase 1: D write + per-(row, wave-64cols) packed bests ----
    // (no lds reads of the main buffer occur after ph8's BAR, so reusing the
    //  first 16 KB for partials is race-free; __syncthreads before combine)
    ull* sMax = (ull*)lds;            // [4][256]  (8 KB)
    ull* sMin = (ull*)(lds + 4096);   // [4][256]  (8 KB, byte offset 8192)
    const int g = lane >> 4;
#pragma unroll
    for (int MH = 0; MH < 2; ++MH)
#pragma unroll
    for (int m = 0; m < 4; ++m) {
        const int row0L = MH * 128 + wr * 64 + m * 16 + g * 4;
        ull kmax[4], kmin[4];
#pragma unroll
        for (int r = 0; r < 4; ++r) { kmax[r] = 0ULL; kmin[r] = ~0ULL; }
#pragma unroll
        for (int NH = 0; NH < 2; ++NH)
#pragma unroll
        for (int n = 0; n < 2; ++n) {
            const int colL = NH * 128 + wc * 32 + n * 16 + fr;
            const int col = colC0 + colL;
            const float sqc = sq[col];
            const int tc = sTgtC[colL];
#pragma unroll
            for (int r = 0; r < 4; ++r) {
                const int rowL = row0L + r;
                const int row = rowC0 + rowL;
                float d2 = sq[row] + sqc - 2.0f * acc[MH][NH][m][n][r];
                float d = sqrtf(fmaxf(d2, 1e-12f));
                D[(size_t)row * N_DIM + col] = d;
                const ull db = (ull)__float_as_uint(d) << 32;
                if (tc == sTgtR[rowL]) {
                    ull k = db | (unsigned)col;
                    if (k > kmax[r]) kmax[r] = k;
                } else {
                    ull k = db | (unsigned)(~col);
                    if (k < kmin[r]) kmin[r] = k;
                }
            }
        }
#pragma unroll
        for (int off = 1; off < 16; off <<= 1) {
#pragma unroll
            for (int r = 0; r < 4; ++r) {
                ull o = __shfl_xor(kmax[r], off);
                if (o > kmax[r]) kmax[r] = o;
                o = __shfl_xor(kmin[r], off);
                if (o < kmin[r]) kmin[r] = o;
            }
        }
        if (fr == 0) {
#pragma unroll
            for (int r = 0; r < 4; ++r) {
                sMax[wc * 256 + row0L + r] = kmax[r];
                sMin[wc * 256 + row0L + r] = kmin[r];
            }
        }
    }
    __syncthreads();
    // ---- epilogue phase 2: combine 4 waves, one atomic pair per row --------
    if (tid < 256) {
        ull km = 0ULL, kn = ~0ULL;
#pragma unroll
        for (int w2 = 0; w2 < 4; ++w2) {
            ull a = sMax[w2 * 256 + tid]; if (a > km) km = a;
            ull b = sMin[w2 * 256 + tid]; if (b < kn) kn = b;
        }
        atomicMax(&gMax[rowC0 + tid], km);
        atomicMin(&gMin[rowC0 + tid], kn);
    }
}

// ---------------- Kernel 2: third-class scan on row q[i], per-row loss -----
__global__ __launch_bounds__(256)
void pass2(const float* __restrict__ D, const int* __restrict__ tgt,
           const ull* __restrict__ gMax, const ull* __restrict__ gMin,
           float* __restrict__ lossArr) {
    const int i = blockIdx.x, tid = threadIdx.x;
    const ull km = gMax[i], kn = gMin[i];
    const float ap = __uint_as_float((unsigned)(km >> 32));
    const int p = (int)(unsigned)(km & 0xFFFFFFFFu);
    const float an = __uint_as_float((unsigned)(kn >> 32));
    const int q = (int)(~(unsigned)(kn & 0xFFFFFFFFu));
    const int ti = tgt[i], lq = tgt[q];
    const float* rowq = D + (size_t)q * N_DIM;
    float bmin = INFINITY; int br = -1;
#pragma unroll
    for (int it = 0; it < 4; ++it) {
        const int j0 = (it * 256 + tid) * 4;
        floatx4 d = *(const floatx4*)(rowq + j0);
        intx4 t4 = *(const intx4*)(tgt + j0);
#pragma unroll
        for (int e = 0; e < 4; ++e) {
            const int j = j0 + e; const float dv = d[e];
            if (t4[e] != ti && t4[e] != lq) {
                if (dv < bmin || (dv == bmin && j > br)) { bmin = dv; br = j; }
            }
        }
    }
    __shared__ float sm[256]; __shared__ int si[256];
    sm[tid] = bmin; si[tid] = br;
    __syncthreads();
    for (int off = 128; off; off >>= 1) {
        if (tid < off) {
            float v = sm[tid + off]; int ix = si[tid + off];
            if (v < sm[tid] || (v == sm[tid] && ix > si[tid])) { sm[tid] = v; si[tid] = ix; }
        }
        __syncthreads();
    }
    if (tid == 0) {
        const int r = si[0]; const float okmin = sm[0];
        const float an2 = D[(size_t)p * N_DIM + q];
        const float an3 = D[(size_t)i * N_DIM + r];
        lossArr[i] = fmaxf(ap - an, 0.f) + fabsf(an - an2) + fabsf(an3 - okmin);
    }
}

// ---------------- Kernel 3: final sum / n -----------------------------------
__global__ __launch_bounds__(256)
void finred(const float* __restrict__ lossArr, float* __restrict__ out) {
    const int tid = threadIdx.x;
    float s = 0.f;
    for (int j = tid; j < N_DIM; j += 256) s += lossArr[j];
#pragma unroll
    for (int off = 32; off; off >>= 1) s += __shfl_down(s, off);
    __shared__ float w[4];
    const int wave = tid >> 6, lane = tid & 63;
    if (lane == 0) w[wave] = s;
    __syncthreads();
    if (tid == 0) out[0] = (w[0] + w[1] + w[2] + w[3]) * (1.0f / (float)N_DIM);
}

extern "C" void kernel_launch(void* const* d_in, const int* in_sizes, int n_in,
                              void* d_out, int out_size, void* d_ws, size_t ws_size,
                              hipStream_t stream) {
    const float* X = (const float*)d_in[0];
    const int* tgt = (const int*)d_in[1];
    float* out = (float*)d_out;

    char* w = (char*)d_ws;
    unsigned short* Abf = (unsigned short*)w;                 // 16 MB
    float* D = (float*)(w + ((size_t)16 << 20));              // 64 MB
    float* sq = (float*)(w + ((size_t)80 << 20));             // 16 KB
    float* lossArr = sq + N_DIM;                              // 16 KB
    ull* gMax = (ull*)(lossArr + N_DIM);                      // 32 KB
    ull* gMin = gMax + N_DIM;                                 // 32 KB

    hipMemsetAsync(gMax, 0x00, N_DIM * sizeof(ull), stream);
    hipMemsetAsync(gMin, 0xFF, N_DIM * sizeof(ull), stream);
    prep_kernel<<<N_DIM, 256, 0, stream>>>(X, Abf, sq);
    gemm_dist<<<256, 512, 0, stream>>>(Abf, sq, tgt, D, gMax, gMin);
    pass2<<<N_DIM, 256, 0, stream>>>(D, tgt, gMax, gMin, lossArr);
    finred<<<1, 256, 0, stream>>>(lossArr, out);
}

// Round 8
// 97.741 us; speedup vs baseline: 1.1438x; 1.1438x over previous
//
#include <hip/hip_runtime.h>
#include <hip/hip_bf16.h>
#include <cstdint>

#define N_DIM 4096
#define K_DIM 2048
#define NIT 16   // 32 K-tiles of 64, 2 per iteration

typedef __bf16 bf16x8 __attribute__((ext_vector_type(8)));
typedef float floatx4 __attribute__((ext_vector_type(4)));
typedef unsigned short ushort8 __attribute__((ext_vector_type(8)));
typedef int intx4 __attribute__((ext_vector_type(4)));
typedef unsigned long long ull;

__device__ __forceinline__ unsigned short f2bf(float f) {
    unsigned int u = __builtin_bit_cast(unsigned int, f);
    unsigned int r = (u + 0x7fffu + ((u >> 16) & 1u)) >> 16;  // RNE
    return (unsigned short)r;
}

__device__ __forceinline__ void gld_lds16(const void* g, void* l) {
    __builtin_amdgcn_global_load_lds(
        (const __attribute__((address_space(1))) unsigned int*)g,
        (__attribute__((address_space(3))) unsigned int*)l,
        16, 0, 0);
}

__device__ __forceinline__ void stage_half(const unsigned short* src, unsigned short* ldsWave) {
    gld_lds16(src, ldsWave);                       // rows 0-63 of the half
    gld_lds16(src + 64 * K_DIM, ldsWave + 4096);   // rows 64-127 (+8192 B)
}

// ---------------- Kernel 0: cast fp32 -> bf16, compute row squared norms ----
__global__ __launch_bounds__(256)
void prep_kernel(const float* __restrict__ X, unsigned short* __restrict__ Abf,
                 float* __restrict__ sq) {
    const int row = blockIdx.x;
    const int tid = threadIdx.x;
    const float* xr = X + (size_t)row * K_DIM;
    floatx4 a = *(const floatx4*)(xr + tid * 8);
    floatx4 b = *(const floatx4*)(xr + tid * 8 + 4);
    float s = 0.f;
    ushort8 o;
#pragma unroll
    for (int e = 0; e < 4; ++e) {
        s += a[e] * a[e] + b[e] * b[e];
        o[e] = f2bf(a[e]);
        o[4 + e] = f2bf(b[e]);
    }
    *(ushort8*)(Abf + (size_t)row * K_DIM + tid * 8) = o;
#pragma unroll
    for (int off = 32; off; off >>= 1) s += __shfl_down(s, off);
    __shared__ float wsum[4];
    const int wave = tid >> 6, lane = tid & 63;
    if (lane == 0) wsum[wave] = s;
    __syncthreads();
    if (tid == 0) sq[row] = wsum[0] + wsum[1] + wsum[2] + wsum[3];
}

// ---------------- Kernel 1: 256x256 8-phase bf16 MFMA GEMM + dist epilogue --
// Round-6 K-loop (best measured: 67 us, 1025 TF, MfmaUtil 42%, 0 bank
// conflicts, VGPR 128). Phase = {ds_reads | stage | [vmcnt] | BAR | MFMA}.
// Stage slots (WAR gap >= 2 phases from region's last read):
//   ph1:b1A1<-(a+1) ph2:b1B0<-(a+1) ph3:b0A0<-(a+2) ph4:b0B1<-(a+2)
//   ph5:b0A1<-(a+2) ph6:b0B0<-(a+2) ph7:b1A0<-(a+3) ph8:b1B1<-(a+3)
// vmcnt(4) before bar_4 and bar_8 only (counted; 0 on last iter).
// XOR-swizzle (row&7)<<4 via pre-swizzled global source + swizzled ds_read.
// LDS byte regions: buf0: A0=0 A1=16384 B0=32768 B1=49152; buf1: +65536.
#define RD_A(OFF) { _Pragma("unroll") for (int m_ = 0; m_ < 4; ++m_) { \
    _Pragma("unroll") for (int kk_ = 0; kk_ < 2; ++kk_) { \
        af[m_][kk_] = *(const bf16x8*)(ldsc + (OFF) + rA[m_] + kb[kk_]); } } }
#define RD_B(OFF) { _Pragma("unroll") for (int n_ = 0; n_ < 2; ++n_) { \
    _Pragma("unroll") for (int kk_ = 0; kk_ < 2; ++kk_) { \
        bfv[n_][kk_] = *(const bf16x8*)(ldsc + (OFF) + rB[n_] + kb[kk_]); } } }
#define MMQ(MH, NH) { _Pragma("unroll") for (int m_ = 0; m_ < 4; ++m_) { \
    _Pragma("unroll") for (int n_ = 0; n_ < 2; ++n_) { \
    _Pragma("unroll") for (int kk_ = 0; kk_ < 2; ++kk_) { \
        acc[MH][NH][m_][n_] = __builtin_amdgcn_mfma_f32_16x16x32_bf16( \
            af[m_][kk_], bfv[n_][kk_], acc[MH][NH][m_][n_], 0, 0, 0); } } } }
#define BAR() __builtin_amdgcn_s_barrier()
#define PRIO1() __builtin_amdgcn_s_setprio(1)
#define PRIO0() __builtin_amdgcn_s_setprio(0)
#define VMCNT4() asm volatile("s_waitcnt vmcnt(4)" ::: "memory")
#define VMCNT0() asm volatile("s_waitcnt vmcnt(0)" ::: "memory")

__global__ __launch_bounds__(512, 2)
void gemm_dist(const unsigned short* __restrict__ Abf, const float* __restrict__ sq,
               float* __restrict__ D) {
    __shared__ unsigned short lds[65536];   // 128 KB
    const char* ldsc = (const char*)lds;
    const int tid = threadIdx.x;
    const int wid = tid >> 6, lane = tid & 63;
    const int wr = wid >> 2, wc = wid & 3;
    const int fr = lane & 15;
    const int key = (fr & 7) << 4;
    const int klin = (lane >> 4) << 4;     // byte offset of 16B k-slot
    int kb[2];
    kb[0] = klin ^ key;
    kb[1] = (64 | klin) ^ key;
    int rA[4], rB[2];
#pragma unroll
    for (int m = 0; m < 4; ++m) rA[m] = (wr * 64 + m * 16 + fr) * 128;
#pragma unroll
    for (int n = 0; n < 2; ++n) rB[n] = (wc * 32 + n * 16 + fr) * 128;

    const int swz = (blockIdx.x & 7) * 32 + (blockIdx.x >> 3);  // XCD-chunked
    const int bi = swz >> 4, bj = swz & 15;
    const int rowC0 = bi * 256, colC0 = bj * 256;

    // per-thread staging source (inverse-swizzled k: linear LDS + swz read = identity)
    const int srow = tid >> 3;
    const int ksrc = ((tid & 7) ^ (srow & 7)) << 3;
    const unsigned short* aSt = Abf + (size_t)(rowC0 + srow) * K_DIM + ksrc;
    const unsigned short* bSt = Abf + (size_t)(colC0 + srow) * K_DIM + ksrc;
    // wave-uniform LDS stage bases (ushort offsets)
    unsigned short* Lb0A0 = lds + 0     + wid * 512;
    unsigned short* Lb0A1 = lds + 8192  + wid * 512;
    unsigned short* Lb0B0 = lds + 16384 + wid * 512;
    unsigned short* Lb0B1 = lds + 24576 + wid * 512;
    unsigned short* Lb1A0 = lds + 32768 + wid * 512;
    unsigned short* Lb1A1 = lds + 40960 + wid * 512;
    unsigned short* Lb1B0 = lds + 49152 + wid * 512;
    unsigned short* Lb1B1 = lds + 57344 + wid * 512;

    floatx4 acc[2][2][4][2];
#pragma unroll
    for (int a0 = 0; a0 < 2; ++a0)
#pragma unroll
    for (int a1 = 0; a1 < 2; ++a1)
#pragma unroll
    for (int a2 = 0; a2 < 4; ++a2)
#pragma unroll
    for (int a3 = 0; a3 < 2; ++a3) acc[a0][a1][a2][a3] = (floatx4){0.f, 0.f, 0.f, 0.f};
    bf16x8 af[4][2], bfv[2][2];

    // prologue: t0 {A0,B0,B1,A1} + t1 {A0,B1}; vmcnt(4) = t0 fully landed
    stage_half(aSt,               Lb0A0);
    stage_half(bSt,               Lb0B0);
    stage_half(bSt + 262144,      Lb0B1);
    stage_half(aSt + 262144,      Lb0A1);
    stage_half(aSt + 64,          Lb1A0);
    stage_half(bSt + 262144 + 64, Lb1B1);
    VMCNT4();
    BAR();

    for (int it = 0; it < NIT; ++it) {
        const int t64 = it * 128;           // k-elem base of tile a=2*it
        const bool pf = (it < NIT - 1);
        // ph1: reads A0,B0 | stage (a+1).A1 -> b1A1 | BAR | MMQ(0,0)
        RD_A(0); RD_B(32768);
        stage_half(aSt + 262144 + t64 + 64, Lb1A1);
        BAR(); PRIO1(); MMQ(0, 0); PRIO0();
        // ph2: reads B1 | stage (a+1).B0 -> b1B0 | BAR | MMQ(0,1)
        RD_B(49152);
        stage_half(bSt + t64 + 64, Lb1B0);
        BAR(); PRIO1(); MMQ(0, 1); PRIO0();
        // ph3: reads A1 | stage (a+2).A0 -> b0A0 | BAR | MMQ(1,1)
        RD_A(16384);
        if (pf) stage_half(aSt + t64 + 128, Lb0A0);
        BAR(); PRIO1(); MMQ(1, 1); PRIO0();
        // ph4: reads B0 | stage (a+2).B1 -> b0B1 | vmcnt | BAR | MMQ(1,0)
        RD_B(32768);
        if (pf) stage_half(bSt + 262144 + t64 + 128, Lb0B1);
        if (pf) { VMCNT4(); } else { VMCNT0(); }
        BAR(); PRIO1(); MMQ(1, 0); PRIO0();
        // ph5: reads A0',B0' | stage (a+2).A1 -> b0A1 | BAR | MMQ(0,0)
        RD_A(65536); RD_B(98304);
        if (pf) stage_half(aSt + 262144 + t64 + 128, Lb0A1);
        BAR(); PRIO1(); MMQ(0, 0); PRIO0();
        // ph6: reads B1' | stage (a+2).B0 -> b0B0 | BAR | MMQ(0,1)
        RD_B(114688);
        if (pf) stage_half(bSt + t64 + 128, Lb0B0);
        BAR(); PRIO1(); MMQ(0, 1); PRIO0();
        // ph7: reads A1' | stage (a+3).A0 -> b1A0 | BAR | MMQ(1,1)
        RD_A(81920);
        if (pf) stage_half(aSt + t64 + 192, Lb1A0);
        BAR(); PRIO1(); MMQ(1, 1); PRIO0();
        // ph8: reads B0' | stage (a+3).B1 -> b1B1 | vmcnt | BAR | MMQ(1,0)
        RD_B(98304);
        if (pf) stage_half(bSt + 262144 + t64 + 192, Lb1B1);
        if (pf) { VMCNT4(); } else { VMCNT0(); }
        BAR(); PRIO1(); MMQ(1, 0); PRIO0();
    }

    // epilogue: D[i][j] = sqrt(max(sq_i + sq_j - 2*dot, 1e-12))
#pragma unroll
    for (int MH = 0; MH < 2; ++MH)
#pragma unroll
    for (int NH = 0; NH < 2; ++NH)
#pragma unroll
    for (int m = 0; m < 4; ++m)
#pragma unroll
    for (int n = 0; n < 2; ++n) {
        const int col = colC0 + NH * 128 + wc * 32 + n * 16 + fr;
        const int row0 = rowC0 + MH * 128 + wr * 64 + m * 16 + (lane >> 4) * 4;
        const float sqc = sq[col];
#pragma unroll
        for (int r = 0; r < 4; ++r) {
            float d2 = sq[row0 + r] + sqc - 2.0f * acc[MH][NH][m][n][r];
            D[(size_t)(row0 + r) * N_DIM + col] = sqrtf(fmaxf(d2, 1e-12f));
        }
    }
}

// ---------------- Kernel 2: fused row stats + third-class scan + loss -------
// Block i: phase 1 scans row i -> ap/p (hardest pos, last-tie) and an/q
// (hardest neg, last-tie) via packed (f32bits<<32 | idx) keys (d > 0 so
// float bits are monotone; ~idx encodes last-tie for mins). Phase 2 scans
// row q with the third-class mask -> okmin/r. Then loss_i. Replaces the
// old rowstats+pass2 pair (one launch, no gMax/gMin round trip, no memsets).
__global__ __launch_bounds__(256)
void stats_loss(const float* __restrict__ D, const int* __restrict__ tgt,
                float* __restrict__ lossArr) {
    const int i = blockIdx.x, tid = threadIdx.x;
    const int ti = tgt[i];
    const float* row = D + (size_t)i * N_DIM;
    ull kmax = 0ULL, kmin = ~0ULL;
#pragma unroll
    for (int it = 0; it < 4; ++it) {
        const int j0 = (it * 256 + tid) * 4;
        floatx4 d = *(const floatx4*)(row + j0);
        intx4 t4 = *(const intx4*)(tgt + j0);
#pragma unroll
        for (int e = 0; e < 4; ++e) {
            const int j = j0 + e;
            const ull db = (ull)__float_as_uint(d[e]) << 32;
            if (t4[e] == ti) { ull k = db | (unsigned)j;  if (k > kmax) kmax = k; }
            else             { ull k = db | (unsigned)~j; if (k < kmin) kmin = k; }
        }
    }
    __shared__ ull sM[256], sN[256];
    sM[tid] = kmax; sN[tid] = kmin;
    __syncthreads();
    for (int off = 128; off; off >>= 1) {
        if (tid < off) {
            if (sM[tid + off] > sM[tid]) sM[tid] = sM[tid + off];
            if (sN[tid + off] < sN[tid]) sN[tid] = sN[tid + off];
        }
        __syncthreads();
    }
    const ull km = sM[0], kn = sN[0];
    const float ap = __uint_as_float((unsigned)(km >> 32));
    const int p = (int)(unsigned)(km & 0xFFFFFFFFu);
    const float an = __uint_as_float((unsigned)(kn >> 32));
    const int q = (int)~(unsigned)(kn & 0xFFFFFFFFu);
    __syncthreads();   // all threads have read sM[0]/sN[0]; safe to reuse sN

    // phase 2: third-class min over row q (labels != ti and != tgt[q])
    const int lq = tgt[q];
    const float* rowq = D + (size_t)q * N_DIM;
    ull kr = ~0ULL;
#pragma unroll
    for (int it = 0; it < 4; ++it) {
        const int j0 = (it * 256 + tid) * 4;
        floatx4 d = *(const floatx4*)(rowq + j0);
        intx4 t4 = *(const intx4*)(tgt + j0);
#pragma unroll
        for (int e = 0; e < 4; ++e) {
            const int j = j0 + e;
            if (t4[e] != ti && t4[e] != lq) {
                ull k = ((ull)__float_as_uint(d[e]) << 32) | (unsigned)~j;
                if (k < kr) kr = k;
            }
        }
    }
    sN[tid] = kr;
    __syncthreads();
    for (int off = 128; off; off >>= 1) {
        if (tid < off) { if (sN[tid + off] < sN[tid]) sN[tid] = sN[tid + off]; }
        __syncthreads();
    }
    if (tid == 0) {
        const ull kk = sN[0];
        const float okmin = __uint_as_float((unsigned)(kk >> 32));
        const int r = (int)~(unsigned)(kk & 0xFFFFFFFFu);
        const float an2 = D[(size_t)p * N_DIM + q];
        const float an3 = D[(size_t)i * N_DIM + r];
        lossArr[i] = fmaxf(ap - an, 0.f) + fabsf(an - an2) + fabsf(an3 - okmin);
    }
}

// ---------------- Kernel 3: final sum / n -----------------------------------
__global__ __launch_bounds__(256)
void finred(const float* __restrict__ lossArr, float* __restrict__ out) {
    const int tid = threadIdx.x;
    float s = 0.f;
    for (int j = tid; j < N_DIM; j += 256) s += lossArr[j];
#pragma unroll
    for (int off = 32; off; off >>= 1) s += __shfl_down(s, off);
    __shared__ float w[4];
    const int wave = tid >> 6, lane = tid & 63;
    if (lane == 0) w[wave] = s;
    __syncthreads();
    if (tid == 0) out[0] = (w[0] + w[1] + w[2] + w[3]) * (1.0f / (float)N_DIM);
}

extern "C" void kernel_launch(void* const* d_in, const int* in_sizes, int n_in,
                              void* d_out, int out_size, void* d_ws, size_t ws_size,
                              hipStream_t stream) {
    const float* X = (const float*)d_in[0];
    const int* tgt = (const int*)d_in[1];
    float* out = (float*)d_out;

    char* w = (char*)d_ws;
    unsigned short* Abf = (unsigned short*)w;                 // 16 MB
    float* D = (float*)(w + ((size_t)16 << 20));              // 64 MB
    float* sq = (float*)(w + ((size_t)80 << 20));             // 16 KB
    float* lossArr = sq + N_DIM;                              // 16 KB

    prep_kernel<<<N_DIM, 256, 0, stream>>>(X, Abf, sq);
    gemm_dist<<<256, 512, 0, stream>>>(Abf, sq, D);
    stats_loss<<<N_DIM, 256, 0, stream>>>(D, tgt, lossArr);
    finred<<<1, 256, 0, stream>>>(lossArr, out);
}

// Round 9
// 87.627 us; speedup vs baseline: 1.2758x; 1.1154x over previous
//
#include <hip/hip_runtime.h>
#include <hip/hip_bf16.h>
#include <cstdint>

#define N_DIM 4096
#define K_DIM 2048           // i8 bytes per row
#define NKT 32               // 32 K-tiles of 64
#define QSCALE 24.0f
#define QINV (1.0f / 24.0f)

typedef float floatx4 __attribute__((ext_vector_type(4)));
typedef int intx4 __attribute__((ext_vector_type(4)));
typedef unsigned long long ull;

__device__ __forceinline__ void gld_lds16(const void* g, void* l) {
    __builtin_amdgcn_global_load_lds(
        (const __attribute__((address_space(1))) unsigned int*)g,
        (__attribute__((address_space(3))) unsigned int*)l,
        16, 0, 0);
}

// ---------------- Kernel 0: quantize fp32 -> int8 (scale 24), int row norms -
__global__ __launch_bounds__(256)
void prep_kernel(const float* __restrict__ X, char* __restrict__ Q,
                 int* __restrict__ sqi) {
    const int row = blockIdx.x;
    const int tid = threadIdx.x;
    const float* xr = X + (size_t)row * K_DIM;
    floatx4 a = *(const floatx4*)(xr + tid * 8);
    floatx4 b = *(const floatx4*)(xr + tid * 8 + 4);
    int s = 0;
    unsigned lo = 0, hi = 0;
#pragma unroll
    for (int e = 0; e < 4; ++e) {
        int v = __float2int_rn(a[e] * QSCALE);
        v = min(127, max(-127, v));
        s += v * v;
        lo |= ((unsigned)(v & 0xff)) << (8 * e);
        int w = __float2int_rn(b[e] * QSCALE);
        w = min(127, max(-127, w));
        s += w * w;
        hi |= ((unsigned)(w & 0xff)) << (8 * e);
    }
    *(int2*)(Q + (size_t)row * K_DIM + tid * 8) = make_int2((int)lo, (int)hi);
#pragma unroll
    for (int off = 32; off; off >>= 1) s += __shfl_down(s, off);
    __shared__ int wsum[4];
    const int wave = tid >> 6, lane = tid & 63;
    if (lane == 0) wsum[wave] = s;
    __syncthreads();
    if (tid == 0) sqi[row] = wsum[0] + wsum[1] + wsum[2] + wsum[3];
}

// ---------------- Kernel 1: 256x256 int8 MFMA GEMM + distance epilogue ------
// 512 thr = 8 waves (2Mx4N: wr=wid>>2, wc=wid&3). mfma_i32_16x16x64_i8,
// K-tile = 64 bytes/row. Triple-buffered LDS (3 x 32KB), 2 phases per K-tile:
//   ph1: RD Alo(4 b128)+B(4) | STG B0,B1 of tile t+2 | BAR | 16 MFMA (MH=0)
//   ph2: RD Ahi(4)           | STG A0,A1 of tile t+2 | vmcnt(4) | BAR | 16 MFMA (MH=1)
// WAR gaps: B regions last read ph1(t-1) -> staged ph1(t) (2 phases);
//           A regions last read ph2(t-1) -> staged ph2(t) (2 phases).
// vmcnt(4) per iter retires tile t+1 (4 loads) exactly before iter t+1 reads.
// LDS layout per 8KB region: transposed 16B units, pos16 = ksub*128 + row
// (realized by per-thread source addressing; linear gld_lds dest). Read
// bank-phase = row%8 -> conflict-free, no swizzle needed.
// Fragment layout (i8 16x16x64): lane holds 16 i8, row/col=lane&15,
// k = (lane>>4)*16 + [0..15]; C/D: col=lane&15, row=(lane>>4)*4+r.
#define BAR() __builtin_amdgcn_s_barrier()
#define PRIO1() __builtin_amdgcn_s_setprio(1)
#define PRIO0() __builtin_amdgcn_s_setprio(0)
#define VMCNT4() asm volatile("s_waitcnt vmcnt(4)" ::: "memory")
#define VMCNT0() asm volatile("s_waitcnt vmcnt(0)" ::: "memory")
#define MM8(MHI, AF) { _Pragma("unroll") for (int n_ = 0; n_ < 4; ++n_) { \
    _Pragma("unroll") for (int m_ = 0; m_ < 4; ++m_) { \
        acc[MHI][n_][m_] = __builtin_amdgcn_mfma_i32_16x16x64_i8( \
            AF[m_], bfv[n_], acc[MHI][n_][m_], 0, 0, 0); } } }

__global__ __launch_bounds__(512, 2)
void gemm_dist(const char* __restrict__ Q, const int* __restrict__ sqi,
               float* __restrict__ D) {
    __shared__ char lds[98304];   // 96 KB = 3 bufs x (A0,A1,B0,B1 of 8KB)
    const int tid = threadIdx.x;
    const int wid = tid >> 6, lane = tid & 63;
    const int wr = wid >> 2, wc = wid & 3;
    const int fr = lane & 15, ksub = lane >> 4;

    // read byte-offsets within a region
    int rA[4], rB[4];
#pragma unroll
    for (int m = 0; m < 4; ++m) rA[m] = (ksub * 128 + m * 16 + fr) * 16;
#pragma unroll
    for (int n = 0; n < 4; ++n) rB[n] = (ksub * 128 + (wc & 1) * 64 + n * 16 + fr) * 16;
    const int aRegOff = wr * 8192;                    // A0 or A1 by wave-row
    const int bRegOff = 16384 + (wc >> 1) * 8192;     // B0 or B1 by wave-col

    const int swz = (blockIdx.x & 7) * 32 + (blockIdx.x >> 3);  // XCD-chunked
    const int bi = swz >> 4, bj = swz & 15;
    const int rowC0 = bi * 256, colC0 = bj * 256;

    // staging source: thread t covers region pos16=t -> row=t&127, ksub=t>>7
    const int srow = tid & 127;
    const int sk = (tid >> 7) * 16;
    const char* aSt = Q + (size_t)(rowC0 + srow) * K_DIM + sk;   // A0 rows 0-127
    const char* bSt = Q + (size_t)(colC0 + srow) * K_DIM + sk;   // B0 cols 0-127
    const size_t HALF = (size_t)128 * K_DIM;                     // +128 rows
    char* ldsW = lds + wid * 1024;    // wave-uniform dest base within a region

    intx4 acc[2][4][4];
#pragma unroll
    for (int a0 = 0; a0 < 2; ++a0)
#pragma unroll
    for (int a1 = 0; a1 < 4; ++a1)
#pragma unroll
    for (int a2 = 0; a2 < 4; ++a2) acc[a0][a1][a2] = (intx4){0, 0, 0, 0};
    intx4 aflo[4], afhi[4], bfv[4];

    // prologue: tile0 (buf0) then tile1 (buf1); vmcnt(4) = tile0 landed
    gld_lds16(bSt,               ldsW + 16384);   // t0.B0
    gld_lds16(bSt + HALF,        ldsW + 24576);   // t0.B1
    gld_lds16(aSt,               ldsW + 0);       // t0.A0
    gld_lds16(aSt + HALF,        ldsW + 8192);    // t0.A1
    gld_lds16(bSt + 64,          ldsW + 32768 + 16384);
    gld_lds16(bSt + HALF + 64,   ldsW + 32768 + 24576);
    gld_lds16(aSt + 64,          ldsW + 32768 + 0);
    gld_lds16(aSt + HALF + 64,   ldsW + 32768 + 8192);
    VMCNT4();
    BAR();

    int cb = 0, sb = 2;   // current read buf, staging buf (t+2)
    for (int t = 0; t < NKT; ++t) {
        const bool pf = (t < NKT - 2);
        const char* bufA = lds + cb * 32768 + aRegOff;
        const char* bufBp = lds + cb * 32768 + bRegOff;
        const int koff = (t + 2) * 64;
        char* stB = ldsW + sb * 32768;
        // ph1: RD Alo + B | STG (t+2).B0,B1 | BAR | MFMA MH=0
#pragma unroll
        for (int m = 0; m < 4; ++m) aflo[m] = *(const intx4*)(bufA + rA[m]);
#pragma unroll
        for (int n = 0; n < 4; ++n) bfv[n] = *(const intx4*)(bufBp + rB[n]);
        if (pf) {
            gld_lds16(bSt + koff,        stB + 16384);
            gld_lds16(bSt + HALF + koff, stB + 24576);
        }
        BAR(); PRIO1(); MM8(0, aflo); PRIO0();
        // ph2: RD Ahi | STG (t+2).A0,A1 | vmcnt | BAR | MFMA MH=1
#pragma unroll
        for (int m = 0; m < 4; ++m) afhi[m] = *(const intx4*)(bufA + 1024 + rA[m]);
        if (pf) {
            gld_lds16(aSt + koff,        stB + 0);
            gld_lds16(aSt + HALF + koff, stB + 8192);
            VMCNT4();
        } else {
            VMCNT0();
        }
        BAR(); PRIO1(); MM8(1, afhi); PRIO0();
        cb = (cb == 2) ? 0 : cb + 1;
        sb = (sb == 2) ? 0 : sb + 1;
    }

    // epilogue: D[i][j] = (v>0) ? sqrt(v)/24 : 1e-6, v = sqi+sqj-2*dot (exact)
#pragma unroll
    for (int MH = 0; MH < 2; ++MH)
#pragma unroll
    for (int n = 0; n < 4; ++n) {
        const int col = colC0 + wc * 64 + n * 16 + fr;
        const int sqc = sqi[col];
#pragma unroll
        for (int m = 0; m < 4; ++m) {
            const int row0 = rowC0 + wr * 128 + MH * 64 + m * 16 + ksub * 4;
#pragma unroll
            for (int r = 0; r < 4; ++r) {
                const int v = sqi[row0 + r] + sqc - 2 * acc[MH][n][m][r];
                const float d = (v > 0) ? sqrtf((float)v) * QINV : 1e-6f;
                D[(size_t)(row0 + r) * N_DIM + col] = d;
            }
        }
    }
}

// ---------------- Kernel 2: fused row stats + third-class scan + loss -------
__global__ __launch_bounds__(256)
void stats_loss(const float* __restrict__ D, const int* __restrict__ tgt,
                float* __restrict__ lossArr) {
    const int i = blockIdx.x, tid = threadIdx.x;
    const int ti = tgt[i];
    const float* row = D + (size_t)i * N_DIM;
    ull kmax = 0ULL, kmin = ~0ULL;
#pragma unroll
    for (int it = 0; it < 4; ++it) {
        const int j0 = (it * 256 + tid) * 4;
        floatx4 d = *(const floatx4*)(row + j0);
        intx4 t4 = *(const intx4*)(tgt + j0);
#pragma unroll
        for (int e = 0; e < 4; ++e) {
            const int j = j0 + e;
            const ull db = (ull)__float_as_uint(d[e]) << 32;
            if (t4[e] == ti) { ull k = db | (unsigned)j;  if (k > kmax) kmax = k; }
            else             { ull k = db | (unsigned)~j; if (k < kmin) kmin = k; }
        }
    }
    __shared__ ull sM[256], sN[256];
    sM[tid] = kmax; sN[tid] = kmin;
    __syncthreads();
    for (int off = 128; off; off >>= 1) {
        if (tid < off) {
            if (sM[tid + off] > sM[tid]) sM[tid] = sM[tid + off];
            if (sN[tid + off] < sN[tid]) sN[tid] = sN[tid + off];
        }
        __syncthreads();
    }
    const ull km = sM[0], kn = sN[0];
    const float ap = __uint_as_float((unsigned)(km >> 32));
    const int p = (int)(unsigned)(km & 0xFFFFFFFFu);
    const float an = __uint_as_float((unsigned)(kn >> 32));
    const int q = (int)~(unsigned)(kn & 0xFFFFFFFFu);
    __syncthreads();

    const int lq = tgt[q];
    const float* rowq = D + (size_t)q * N_DIM;
    ull kr = ~0ULL;
#pragma unroll
    for (int it = 0; it < 4; ++it) {
        const int j0 = (it * 256 + tid) * 4;
        floatx4 d = *(const floatx4*)(rowq + j0);
        intx4 t4 = *(const intx4*)(tgt + j0);
#pragma unroll
        for (int e = 0; e < 4; ++e) {
            const int j = j0 + e;
            if (t4[e] != ti && t4[e] != lq) {
                ull k = ((ull)__float_as_uint(d[e]) << 32) | (unsigned)~j;
                if (k < kr) kr = k;
            }
        }
    }
    sN[tid] = kr;
    __syncthreads();
    for (int off = 128; off; off >>= 1) {
        if (tid < off) { if (sN[tid + off] < sN[tid]) sN[tid] = sN[tid + off]; }
        __syncthreads();
    }
    if (tid == 0) {
        const ull kk = sN[0];
        const float okmin = __uint_as_float((unsigned)(kk >> 32));
        const int r = (int)~(unsigned)(kk & 0xFFFFFFFFu);
        const float an2 = D[(size_t)p * N_DIM + q];
        const float an3 = D[(size_t)i * N_DIM + r];
        lossArr[i] = fmaxf(ap - an, 0.f) + fabsf(an - an2) + fabsf(an3 - okmin);
    }
}

// ---------------- Kernel 3: final sum / n -----------------------------------
__global__ __launch_bounds__(256)
void finred(const float* __restrict__ lossArr, float* __restrict__ out) {
    const int tid = threadIdx.x;
    float s = 0.f;
    for (int j = tid; j < N_DIM; j += 256) s += lossArr[j];
#pragma unroll
    for (int off = 32; off; off >>= 1) s += __shfl_down(s, off);
    __shared__ float w[4];
    const int wave = tid >> 6, lane = tid & 63;
    if (lane == 0) w[wave] = s;
    __syncthreads();
    if (tid == 0) out[0] = (w[0] + w[1] + w[2] + w[3]) * (1.0f / (float)N_DIM);
}

extern "C" void kernel_launch(void* const* d_in, const int* in_sizes, int n_in,
                              void* d_out, int out_size, void* d_ws, size_t ws_size,
                              hipStream_t stream) {
    const float* X = (const float*)d_in[0];
    const int* tgt = (const int*)d_in[1];
    float* out = (float*)d_out;

    char* w = (char*)d_ws;
    char* Q = w;                                              // 8 MB int8
    float* D = (float*)(w + ((size_t)16 << 20));              // 64 MB
    int* sqi = (int*)(w + ((size_t)80 << 20));                // 16 KB
    float* lossArr = (float*)(sqi + N_DIM);                   // 16 KB

    prep_kernel<<<N_DIM, 256, 0, stream>>>(X, Q, sqi);
    gemm_dist<<<256, 512, 0, stream>>>(Q, sqi, D);
    stats_loss<<<N_DIM, 256, 0, stream>>>(D, tgt, lossArr);
    finred<<<1, 256, 0, stream>>>(lossArr, out);
}